// Round 4
// baseline (156.554 us; speedup 1.0000x reference)
//
#include <hip/hip_runtime.h>

// Problem constants
#define IMG_H 512
#define IMG_W 512
#define NKH 32
#define NKW 32
#define NK (NKH * NKW)
#define BATCH 64
#define NSTRIP 33          // 16-row strips of the 528-row padded image
#define G 2                // batches per block in main kernel

// ---------------------------------------------------------------------------
// Kernel 0: weight transpose/masking into W2[tr][rr][e][t] (float4 chunks).
// Main-kernel thread t of strip tr reads wreg[rr][e] = W2[tr][rr*8+e][t],
// fully coalesced. Zero-baked: padding cols (image col <0 or >=512) and
// invalid window halves (tr=32,h=0 / tr=0,h=1).
// t decode: h = t>>7, nc = (t>>2)&31, rsub = t&3. Weight row = h*16 + rsub+4*rr.
// ---------------------------------------------------------------------------
__global__ __launch_bounds__(256)
void bslc_wxform_kernel(const float* __restrict__ w, float4* __restrict__ W2)
{
    const int idx = blockIdx.x * 256 + threadIdx.x;   // 0 .. 33*8192-1
    const int t    = idx & 255;
    const int e    = (idx >> 8) & 7;
    const int rr   = (idx >> 11) & 3;
    const int tr   = idx >> 13;

    const int h    = t >> 7;
    const int nc   = (t >> 2) & 31;
    const int rsub = t & 3;
    const int nr   = tr - h;

    float4 v = make_float4(0.f, 0.f, 0.f, 0.f);
    const int ic0 = 16 * nc - 8 + 4 * e;              // image col of this chunk
    if (nr >= 0 && nr < NKH && ic0 >= 0 && ic0 < IMG_W) {
        const int n = nr * NKW + nc;
        const size_t off = (size_t)n * 1024 + (size_t)h * 512
                         + (size_t)(rsub + 4 * rr) * 32 + 4 * e;
        v = *reinterpret_cast<const float4*>(w + off);
    }
    W2[idx] = v;
}

// ---------------------------------------------------------------------------
// Main kernel: block = strip tr (16 padded rows = image rows 16tr-8..16tr+7)
// x G batches. Stage strip as ONE aligned contiguous 32KB stream into LDS
// (rotation-swizzled per row: chunk c of row r at (c+r)&127). Thread t
// computes the full 128-elem (4 rows x 32 cols) half-window partial for
// (h, nc, rsub); 4-lane shfl reduce; rsub==0 writes P[b][tr][h][nc].
// Bijective -> no atomics. Invalid halves compute 0 against zeroed weights
// and write never-read P slots (branch-free).
// ---------------------------------------------------------------------------
__global__ __launch_bounds__(256, 4)
void bslc_strip_kernel(const float* __restrict__ x,
                       const float4* __restrict__ W2,
                       float* __restrict__ P)
{
    __shared__ float4 xs[16 * 128];    // 32 KiB
    const int tr = blockIdx.x;         // 0..32
    const int bg = blockIdx.y;         // 0..31
    const int t  = threadIdx.x;

    const int h    = t >> 7;
    const int nc   = (t >> 2) & 31;
    const int rsub = t & 3;

    // Coalesced weight load: 32 x float4 in registers, reused across G batches.
    float4 wreg[4][8];
    {
        const float4* wt = W2 + (size_t)tr * 8192 + t;
#pragma unroll
        for (int rr = 0; rr < 4; ++rr)
#pragma unroll
            for (int e = 0; e < 8; ++e)
                wreg[rr][e] = wt[(rr * 8 + e) * 256];
    }

    const int r0img = tr * 16 - 8;
    const bool interior = (tr >= 1) && (tr <= 31);

    for (int bi = 0; bi < G; ++bi) {
        const int b = bg * G + bi;
        const float* xb = x + (size_t)b * (IMG_H * IMG_W);

        // ---- stage: 2048 chunks, linear & aligned ----
        if (interior) {
            const float4* src = reinterpret_cast<const float4*>(
                xb + (size_t)r0img * IMG_W);
#pragma unroll
            for (int i = 0; i < 8; ++i) {
                const int g  = i * 256 + t;
                const int r  = g >> 7;
                const int c  = g & 127;
                xs[r * 128 + ((c + r) & 127)] = src[g];
            }
        } else {
#pragma unroll
            for (int i = 0; i < 8; ++i) {
                const int g  = i * 256 + t;
                const int r  = g >> 7;
                const int c  = g & 127;
                const int rimg = r0img + r;
                float4 v = make_float4(0.f, 0.f, 0.f, 0.f);
                if (rimg >= 0 && rimg < IMG_H)
                    v = *reinterpret_cast<const float4*>(
                        xb + (size_t)rimg * IMG_W + 4 * c);
                xs[r * 128 + ((c + r) & 127)] = v;
            }
        }
        __syncthreads();

        // ---- compute: 4 rows x 8 chunks, branch-free ----
        float a0 = 0.f, a1 = 0.f, a2 = 0.f, a3 = 0.f;
#pragma unroll
        for (int rr = 0; rr < 4; ++rr) {
            const int r = rsub + 4 * rr;
            const int cbase = 4 * nc - 2 + r;          // chunk base + rotation
#pragma unroll
            for (int e = 0; e < 8; ++e) {
                const float4 xv = xs[r * 128 + ((cbase + e) & 127)];
                const float4 wv = wreg[rr][e];
                a0 = fmaf(xv.x, wv.x, a0);
                a1 = fmaf(xv.y, wv.y, a1);
                a2 = fmaf(xv.z, wv.z, a2);
                a3 = fmaf(xv.w, wv.w, a3);
            }
        }
        float s = (a0 + a1) + (a2 + a3);
        s += __shfl_xor(s, 1, 64);
        s += __shfl_xor(s, 2, 64);
        if (rsub == 0)
            P[((size_t)b * NSTRIP + tr) * 64 + h * 32 + nc] = s;
        __syncthreads();
    }
}

// out[b][n] = bias[n] + P[b][nr][0][nc] + P[b][nr+1][1][nc]
__global__ __launch_bounds__(256)
void bslc_reduce_kernel(const float* __restrict__ P,
                        const float* __restrict__ bias,
                        float* __restrict__ out)
{
    const int g = blockIdx.x * 256 + threadIdx.x;   // b*1024 + n
    const int b = g >> 10;
    const int n = g & (NK - 1);
    const int nr = n >> 5, nc = n & 31;
    const float top = P[((size_t)b * NSTRIP + nr) * 64 + nc];
    const float bot = P[((size_t)b * NSTRIP + nr + 1) * 64 + 32 + nc];
    out[g] = top + bot + bias[n];
}

extern "C" void kernel_launch(void* const* d_in, const int* in_sizes, int n_in,
                              void* d_out, int out_size, void* d_ws, size_t ws_size,
                              hipStream_t stream) {
    const float* x    = (const float*)d_in[0];  // (64,1,512,512) fp32
    const float* wgt  = (const float*)d_in[1];  // (1024,1024) fp32
    const float* bias = (const float*)d_in[2];  // (1024,) fp32
    float* out        = (float*)d_out;          // (64,32,32) fp32

    float*  P  = (float*)d_ws;                               // 64*33*64 = 528 KB
    float4* W2 = (float4*)((char*)d_ws + 64 * NSTRIP * 64 * sizeof(float));
                                                             // 33*8192 float4 = 4.3 MB

    bslc_wxform_kernel<<<dim3(NSTRIP * 8192 / 256), 256, 0, stream>>>(wgt, W2);
    bslc_strip_kernel<<<dim3(NSTRIP, BATCH / G), 256, 0, stream>>>(x, W2, P);
    bslc_reduce_kernel<<<dim3(BATCH * NK / 256), 256, 0, stream>>>(P, bias, out);
}

// Round 5
// 108.746 us; speedup vs baseline: 1.4396x; 1.4396x over previous
//
#include <hip/hip_runtime.h>

// Problem constants
#define IMG_H 512
#define IMG_W 512
#define NKH 32
#define NKW 32
#define NK 1024
#define BATCH 64
#define NTT 33               // 16x16 tiles per dim of 528x528 padded image
#define NTILE (NTT * NTT)    // 1089
#define NBLK (NTILE * 2)     // 2178 (x2 batch groups)

// Tile (tr,tc) = quadrant (qr,qc) of window (tr-qr, tc-qc): bijective, so each
// partial P[tile][q][b] is written exactly once (no atomics, no init).
//
// Block = one tile x 32 batches. LDS 32KB -> 4 blocks/CU (launch_bounds cap).
// Stage: thread t, iter i: batch b = 4i+wv (wave-uniform), chunk kk = lane;
//        LDS slot xt[kk][(b+kk)&31] -> 8 words/bank both sides (conflict-free).
// Compute: wave = quadrant q; lane = half*32 + b. Weight address depends only
//        on (q, half) -> 2 addrs/wave-instruction, 16B each (broadcast). Per
//        block weights = 4KB, L2-shared with bg-pair + neighbors (XCD swizzle).
__global__ __launch_bounds__(256, 4)
void bslc_main(const float* __restrict__ x,
               const float* __restrict__ w,
               float* __restrict__ P)
{
    __shared__ float4 xt[64][32];   // 32 KiB

    // Bijective XCD-chunked swizzle (m204): 2178 = 8*272 + 2.
    const int hw   = blockIdx.x;
    const int xcd  = hw & 7, slot = hw >> 3;
    const int q8   = NBLK >> 3, r8 = NBLK & 7;            // 272, 2
    const int work = (xcd < r8 ? xcd * (q8 + 1)
                               : r8 * (q8 + 1) + (xcd - r8) * q8) + slot;

    const int bg  = work & 1;        // batch group (pair adjacent -> L2 weight reuse)
    const int lin = work >> 1;       // tile index, row-major
    const int tr  = lin / NTT, tc = lin % NTT;

    const int t = threadIdx.x, lane = t & 63, wv = t >> 6;

    // ---------------- stage ----------------
    const int r0 = tr * 16 - 8, c0 = tc * 16 - 8;
    const int kk = lane;                       // tile chunk: row kk>>2, col4 kk&3
    const int rimg = r0 + (kk >> 2);
    const int cimg = c0 + (kk & 3) * 4;
    const bool interior = (tr >= 1) & (tr <= 31) & (tc >= 1) & (tc <= 31);
    const size_t xoff = (size_t)rimg * IMG_W + cimg;

    if (interior) {
#pragma unroll
        for (int i = 0; i < 8; ++i) {
            const int b = i * 4 + wv;                  // local batch, wave-uniform
            const float4 v = *reinterpret_cast<const float4*>(
                x + (size_t)(bg * 32 + b) * (IMG_H * IMG_W) + xoff);
            xt[kk][(b + kk) & 31] = v;
        }
    } else {
        const bool ok = (rimg >= 0) & (rimg < IMG_H) & (cimg >= 0) & (cimg < IMG_W);
#pragma unroll
        for (int i = 0; i < 8; ++i) {
            const int b = i * 4 + wv;
            float4 v = make_float4(0.f, 0.f, 0.f, 0.f);
            if (ok)
                v = *reinterpret_cast<const float4*>(
                    x + (size_t)(bg * 32 + b) * (IMG_H * IMG_W) + xoff);
            xt[kk][(b + kk) & 31] = v;
        }
    }
    __syncthreads();

    // ---------------- compute ----------------
    const int qr = wv >> 1, qc = wv & 1;
    const int nr = tr - qr, nc = tc - qc;
    if (nr < 0 || nr >= NKH || nc < 0 || nc >= NKW) return;  // wave-uniform exit

    const int n    = nr * NKW + nc;
    const int half = lane >> 5;
    const int b    = lane & 31;
    // Window weight rows qr*16 + half*8 + (j>>2), cols qc*16 + (j&3)*4.
    const float* wb = w + (size_t)n * 1024
                    + (size_t)(qr * 16 + half * 8) * 32 + qc * 16;

    float a0 = 0.f, a1 = 0.f, a2 = 0.f, a3 = 0.f;
#pragma unroll
    for (int j = 0; j < 32; ++j) {
        const int kq = half * 32 + j;
        const float4 xv  = xt[kq][(b + kq) & 31];
        const float4 wv4 = *reinterpret_cast<const float4*>(
            wb + (j >> 2) * 32 + (j & 3) * 4);         // imm offsets, 2 addrs/wave
        a0 = fmaf(xv.x, wv4.x, a0);
        a1 = fmaf(xv.y, wv4.y, a1);
        a2 = fmaf(xv.z, wv4.z, a2);
        a3 = fmaf(xv.w, wv4.w, a3);
    }
    float s = (a0 + a1) + (a2 + a3);
    s += __shfl_xor(s, 32, 64);                        // combine halves
    if (half == 0)
        P[((size_t)(tr * NTT + tc) * 4 + wv) * 64 + bg * 32 + b] = s;  // coalesced
}

// out[b][n] = bias[n] + sum_q P[(nr+qr, nc+qc)][q][b]
__global__ __launch_bounds__(256)
void bslc_reduce(const float* __restrict__ P,
                 const float* __restrict__ bias,
                 float* __restrict__ out)
{
    const int g = blockIdx.x * 256 + threadIdx.x;   // n*64 + b
    const int n = g >> 6;                           // wave-uniform
    const int b = g & 63;
    const int nr = n >> 5, nc = n & 31;
    float s = bias[n];
#pragma unroll
    for (int qq = 0; qq < 4; ++qq) {
        const int tile = (nr + (qq >> 1)) * NTT + nc + (qq & 1);
        s += P[((size_t)tile * 4 + qq) * 64 + b];   // coalesced across lanes
    }
    out[(size_t)b * NK + n] = s;
}

extern "C" void kernel_launch(void* const* d_in, const int* in_sizes, int n_in,
                              void* d_out, int out_size, void* d_ws, size_t ws_size,
                              hipStream_t stream) {
    const float* x    = (const float*)d_in[0];  // (64,1,512,512) fp32
    const float* wgt  = (const float*)d_in[1];  // (1024,1024) fp32
    const float* bias = (const float*)d_in[2];  // (1024,) fp32
    float* out        = (float*)d_out;          // (64,32,32) fp32
    float* P          = (float*)d_ws;           // 1089*4*64 floats = 1.11 MB

    bslc_main<<<dim3(NBLK), 256, 0, stream>>>(x, wgt, P);
    bslc_reduce<<<dim3(BATCH * NK / 256), 256, 0, stream>>>(P, bias, out);
}